// Round 3
// baseline (113.911 us; speedup 1.0000x reference)
//
#include <hip/hip_runtime.h>
#include <hip/hip_bf16.h>

typedef float f32x4 __attribute__((ext_vector_type(4)));
typedef __bf16 bf16x8 __attribute__((ext_vector_type(8)));
typedef unsigned short ushort_t;

#define SEQ 2048
#define BATCH 2
#define EMS 256
#define NHEAD 8
#define HEAD 32
#define BH (BATCH*NHEAD)

static __device__ __forceinline__ ushort_t f2bfbits(float f) {
    unsigned int u = __float_as_uint(f);
    u += 0x7fffu + ((u >> 16) & 1u);   // round-to-nearest-even
    return (ushort_t)(u >> 16);
}

static __device__ __forceinline__ unsigned cvtpk(float lo, float hi) {
    unsigned r;
    asm("v_cvt_pk_bf16_f32 %0, %1, %2" : "=v"(r) : "v"(lo), "v"(hi));
    return r;
}

static __device__ __forceinline__ bf16x8 cvt8(const float* p) {
    float4 a = *reinterpret_cast<const float4*>(p);
    float4 b = *reinterpret_cast<const float4*>(p + 4);
    union { bf16x8 v; ushort_t u[8]; } x;
    x.u[0] = f2bfbits(a.x); x.u[1] = f2bfbits(a.y);
    x.u[2] = f2bfbits(a.z); x.u[3] = f2bfbits(a.w);
    x.u[4] = f2bfbits(b.x); x.u[5] = f2bfbits(b.y);
    x.u[6] = f2bfbits(b.z); x.u[7] = f2bfbits(b.w);
    return x.v;
}

// ---------------- QKV projection ----------------
__global__ __launch_bounds__(256) void qkv_proj(
    const float* __restrict__ em,
    const float* __restrict__ Wq, const float* __restrict__ bq,
    const float* __restrict__ Wk, const float* __restrict__ bk,
    const float* __restrict__ Wv, const float* __restrict__ bv,
    ushort_t* __restrict__ Qb, ushort_t* __restrict__ Kb, ushort_t* __restrict__ Vb)
{
    int wid = blockIdx.x * 4 + (threadIdx.x >> 6);
    int l   = threadIdx.x & 63;
    int l15 = l & 15, lq = l >> 4;
    int rb = wid / 12, cg = wid % 12;
    int r0 = rb * 32, c0 = cg * 64;
    int sel = c0 >> 8;                       // 0=Q 1=K 2=V (uniform per wave)
    const float* W    = sel == 0 ? Wq : (sel == 1 ? Wk : Wv);
    const float* bias = sel == 0 ? bq : (sel == 1 ? bk : bv);
    ushort_t*    dst  = sel == 0 ? Qb : (sel == 1 ? Kb : Vb);
    int cb = c0 & 255;

    f32x4 acc[2][4];
    #pragma unroll
    for (int m = 0; m < 2; m++)
        #pragma unroll
        for (int n = 0; n < 4; n++) acc[m][n] = (f32x4){0.f, 0.f, 0.f, 0.f};

    #pragma unroll
    for (int kk = 0; kk < 8; kk++) {
        int k0 = kk * 32;
        bf16x8 af[2];
        #pragma unroll
        for (int m = 0; m < 2; m++)
            af[m] = cvt8(em + (size_t)(r0 + m * 16 + l15) * EMS + k0 + lq * 8);
        bf16x8 bfm[4];
        #pragma unroll
        for (int n = 0; n < 4; n++)
            bfm[n] = cvt8(W + (size_t)(cb + n * 16 + l15) * EMS + k0 + lq * 8);
        #pragma unroll
        for (int m = 0; m < 2; m++)
            #pragma unroll
            for (int n = 0; n < 4; n++)
                acc[m][n] = __builtin_amdgcn_mfma_f32_16x16x32_bf16(af[m], bfm[n], acc[m][n], 0, 0, 0);
    }

    float scale = (sel == 0) ? 0.17677669529663687f : 1.0f;  // 1/sqrt(32) folded into Q
    #pragma unroll
    for (int m = 0; m < 2; m++) {
        #pragma unroll
        for (int n = 0; n < 4; n++) {
            int c = cb + n * 16 + l15;
            float bv_ = bias[c];
            int h = c >> 5, d = c & 31;
            #pragma unroll
            for (int r = 0; r < 4; r++) {
                int row = r0 + m * 16 + lq * 4 + r;   // C/D: row=(l>>4)*4+reg, col=l&15
                int s = row >> 1, b = row & 1;
                float v = (acc[m][n][r] + bv_) * scale;
                dst[((size_t)(b * NHEAD + h) * SEQ + s) * HEAD + d] = f2bfbits(v);
            }
        }
    }
}

// ---------------- V transpose: [bh][s][d] -> [bh][d][s] ----------------
__global__ __launch_bounds__(256) void vtrans(const ushort_t* __restrict__ Vb,
                                              ushort_t* __restrict__ Vt)
{
    __shared__ ushort_t t[HEAD][65];
    int g = blockIdx.x;
    int bh = g & 15, st = g >> 4;
    int s0 = st * 64;
    int tid = threadIdx.x;
    #pragma unroll
    for (int i = 0; i < 8; i++) {
        int idx = i * 256 + tid;
        int sl = idx >> 5, d = idx & 31;
        t[d][sl] = Vb[((size_t)bh * SEQ + s0 + sl) * HEAD + d];
    }
    __syncthreads();
    #pragma unroll
    for (int i = 0; i < 8; i++) {
        int idx = i * 256 + tid;
        int d = idx >> 6, sl = idx & 63;
        Vt[((size_t)bh * HEAD + d) * SEQ + s0 + sl] = t[d][sl];
    }
}

// ---------------- Flash attention: swapped QK^T + intra-block split-K x4 ----
// Block = 1 (b,h,qtile); wave w owns k-quarter w (16 tiles of 32).  Defer-max
// (THR=8): common path has NO cross-lane ops; lsum kept as lane partial.
__global__ __launch_bounds__(256, 6) void attn(
    const ushort_t* __restrict__ Qb, const ushort_t* __restrict__ Kb,
    const ushort_t* __restrict__ Vt, const float* __restrict__ mask,
    float* __restrict__ out)
{
    int g  = blockIdx.x;
    int qt = g >> 4;
    int b  = (g >> 3) & 1;
    int h  = g & 7;
    int bh = b * NHEAD + h;
    int w  = threadIdx.x >> 6;
    int l  = threadIdx.x & 63;
    int qs0 = qt * 16;
    int l15 = l & 15, lq = l >> 4;

    __shared__ ushort_t plds[4][16][40];     // P^T transpose tile per wave
    __shared__ float oacc[4][16][34];        // per-wave partial O
    __shared__ float om[4][16], ol[4][16];   // per-wave m, l stats
    ushort_t (*P)[40] = plds[w];

    bf16x8 qf = *reinterpret_cast<const bf16x8*>(
        Qb + ((size_t)bh * SEQ + qs0 + l15) * HEAD + lq * 8);

    f32x4 acc0 = {0.f, 0.f, 0.f, 0.f}, acc1 = {0.f, 0.f, 0.f, 0.f};
    float mrun = -1e30f, lsum = 0.f;   // stats for q=l15 (mrun replicated over lq; lsum lane-partial)

    int k0 = w * (SEQ / 4);
    const float*    mrow  = mask + (size_t)b * SEQ * SEQ + (size_t)(qs0 + l15) * SEQ + k0;
    const ushort_t* kbase = Kb + ((size_t)bh * SEQ + k0 + l15) * HEAD + lq * 8;
    const ushort_t* vbase = Vt + ((size_t)bh * HEAD + l15) * SEQ + k0 + lq * 8;

    // prefetch tile 0
    bf16x8 kc0 = *(const bf16x8*)(kbase);
    bf16x8 kc1 = *(const bf16x8*)(kbase + 16 * HEAD);
    float4 mc0 = *(const float4*)(mrow + lq * 4);
    float4 mc1 = *(const float4*)(mrow + 16 + lq * 4);
    bf16x8 vc0 = *(const bf16x8*)(vbase);
    bf16x8 vc1 = *(const bf16x8*)(vbase + 16 * SEQ);

    const int NT = (SEQ / 4) / 32;   // 16 tiles per wave
    #pragma unroll 2
    for (int kt = 0; kt < NT; kt++) {
        int ks1 = (kt + 1 < NT) ? (kt + 1) * 32 : 0;   // wrap: load discarded
        f32x4 z = {0.f, 0.f, 0.f, 0.f};
        // S^T[k][q]: col=l15=q, rows lq*4+r = k (tile-local), +16 for kc1
        f32x4 s0 = __builtin_amdgcn_mfma_f32_16x16x32_bf16(kc0, qf, z, 0, 0, 0);
        f32x4 s1 = __builtin_amdgcn_mfma_f32_16x16x32_bf16(kc1, qf, z, 0, 0, 0);

        // prefetch next tile (overlaps softmax)
        bf16x8 kn0 = *(const bf16x8*)(kbase + (size_t)ks1 * HEAD);
        bf16x8 kn1 = *(const bf16x8*)(kbase + (size_t)(ks1 + 16) * HEAD);
        float4 mn0 = *(const float4*)(mrow + ks1 + lq * 4);
        float4 mn1 = *(const float4*)(mrow + ks1 + 16 + lq * 4);
        bf16x8 vn0 = *(const bf16x8*)(vbase + ks1);
        bf16x8 vn1 = *(const bf16x8*)(vbase + ks1 + 16 * SEQ);

        float sv[8];
        sv[0] = s0[0] + mc0.x; sv[1] = s0[1] + mc0.y;
        sv[2] = s0[2] + mc0.z; sv[3] = s0[3] + mc0.w;
        sv[4] = s1[0] + mc1.x; sv[5] = s1[1] + mc1.y;
        sv[6] = s1[2] + mc1.z; sv[7] = s1[3] + mc1.w;

        float lmax = fmaxf(fmaxf(fmaxf(sv[0], sv[1]), fmaxf(sv[2], sv[3])),
                           fmaxf(fmaxf(sv[4], sv[5]), fmaxf(sv[6], sv[7])));
        if (__any(lmax > mrun + 8.0f)) {   // rare: defer-max rescale
            float pm = fmaxf(lmax, __shfl_xor(lmax, 16));
            pm = fmaxf(pm, __shfl_xor(pm, 32));
            float nm = fmaxf(mrun, pm);
            float sc = __expf(mrun - nm);
            lsum *= sc;
            #pragma unroll
            for (int r = 0; r < 4; r++) {  // acc rows are q=lq*4+r; sc keyed by l15=q
                float scr = __shfl(sc, (l & 48) | (lq * 4 + r));
                acc0[r] *= scr;
                acc1[r] *= scr;
            }
            mrun = nm;
        }

        float e[8];
        #pragma unroll
        for (int j = 0; j < 8; j++) e[j] = __expf(sv[j] - mrun);
        lsum += ((e[0] + e[1]) + (e[2] + e[3])) + ((e[4] + e[5]) + (e[6] + e[7]));

        // P[q=l15][k]: pairs packed by v_cvt_pk_bf16_f32, two b64 writes
        char* prow = (char*)&P[l15][0];
        *(uint2*)(prow + lq * 8)      = make_uint2(cvtpk(e[0], e[1]), cvtpk(e[2], e[3]));
        *(uint2*)(prow + 32 + lq * 8) = make_uint2(cvtpk(e[4], e[5]), cvtpk(e[6], e[7]));

        asm volatile("s_waitcnt lgkmcnt(0)" ::: "memory");
        __builtin_amdgcn_sched_barrier(0);

        bf16x8 pf = *reinterpret_cast<const bf16x8*>(&P[l15][lq * 8]);
        acc0 = __builtin_amdgcn_mfma_f32_16x16x32_bf16(pf, vc0, acc0, 0, 0, 0);
        acc1 = __builtin_amdgcn_mfma_f32_16x16x32_bf16(pf, vc1, acc1, 0, 0, 0);

        kc0 = kn0; kc1 = kn1; mc0 = mn0; mc1 = mn1; vc0 = vn0; vc1 = vn1;
    }

    // finalize lane-partial lsum across lq replicas (2 shuffles total per kernel)
    lsum += __shfl_xor(lsum, 16);
    lsum += __shfl_xor(lsum, 32);

    // publish partials
    #pragma unroll
    for (int r = 0; r < 4; r++) {
        oacc[w][lq * 4 + r][l15]      = acc0[r];
        oacc[w][lq * 4 + r][16 + l15] = acc1[r];
    }
    if (lq == 0) { om[w][l15] = mrun; ol[w][l15] = lsum; }
    __syncthreads();

    // merge 4 k-quarters: 512 outputs, 2 per thread
    for (int i = threadIdx.x; i < 512; i += 256) {
        int q = i >> 5, d = i & 31;
        float m0 = om[0][q], m1 = om[1][q], m2 = om[2][q], m3 = om[3][q];
        float mg = fmaxf(fmaxf(m0, m1), fmaxf(m2, m3));
        float w0 = __expf(m0 - mg), w1 = __expf(m1 - mg);
        float w2 = __expf(m2 - mg), w3 = __expf(m3 - mg);
        float a = w0 * oacc[0][q][d] + w1 * oacc[1][q][d]
                + w2 * oacc[2][q][d] + w3 * oacc[3][q][d];
        float lg = w0 * ol[0][q] + w1 * ol[1][q] + w2 * ol[2][q] + w3 * ol[3][q];
        out[((size_t)(qs0 + q) * BATCH + b) * EMS + h * HEAD + d] = a / lg;
    }
}

extern "C" void kernel_launch(void* const* d_in, const int* in_sizes, int n_in,
                              void* d_out, int out_size, void* d_ws, size_t ws_size,
                              hipStream_t stream) {
    const float* em  = (const float*)d_in[0];
    const float* mask = (const float*)d_in[1];
    const float* Wq  = (const float*)d_in[2];
    const float* bq  = (const float*)d_in[3];
    const float* Wk  = (const float*)d_in[4];
    const float* bk  = (const float*)d_in[5];
    const float* Wv  = (const float*)d_in[6];
    const float* bv  = (const float*)d_in[7];
    float* out = (float*)d_out;

    ushort_t* Qb = (ushort_t*)d_ws;                       // [BH][S][D] bf16, 2MB
    ushort_t* Kb = Qb + (size_t)BH * SEQ * HEAD;          // 2MB
    ushort_t* Vb = Kb + (size_t)BH * SEQ * HEAD;          // 2MB
    ushort_t* Vt = Vb + (size_t)BH * SEQ * HEAD;          // [BH][D][S] bf16, 2MB

    qkv_proj<<<dim3(384), dim3(256), 0, stream>>>(em, Wq, bq, Wk, bk, Wv, bv, Qb, Kb, Vb);
    vtrans<<<dim3(512), dim3(256), 0, stream>>>(Vb, Vt);
    attn<<<dim3(2048), dim3(256), 0, stream>>>(Qb, Kb, Vt, mask, out);
}